// Round 17
// baseline (557.636 us; speedup 1.0000x reference)
//
#include <hip/hip_runtime.h>
#include <hip/hip_bf16.h>

typedef __bf16 bf16;
typedef __bf16 bf16x8 __attribute__((ext_vector_type(8)));
typedef float f32x4 __attribute__((ext_vector_type(4)));
typedef float f32x16 __attribute__((ext_vector_type(16)));

#define AS3(p) ((__attribute__((address_space(3))) void*)(p))
#define AS1(p) ((const __attribute__((address_space(1))) void*)(p))
#define GLDS16(g,l) __builtin_amdgcn_global_load_lds(AS1(g), AS3(l), 16, 0, 0)
#define MFMA_BF16(a,b,c) __builtin_amdgcn_mfma_f32_16x16x32_bf16((a),(b),(c),0,0,0)
#define MFMA32(a,b,c) __builtin_amdgcn_mfma_f32_32x32x16_bf16((a),(b),(c),0,0,0)
#define SCHED_FENCE() do { __builtin_amdgcn_sched_barrier(0); asm volatile("" ::: "memory"); } while (0)

constexpr int S_ = 2048;
constexpr int H_ = 16;
constexpr int KVL_ = 512;
constexpr int ROPE_ = 64;
constexpr int VD_ = 128;
constexpr int DQK_ = 576;           // KVL + ROPE
constexpr int QKV_N = 2176;         // merged q_a(1536) + ckv(512) + krope(64) + pad(64)
constexpr float SCALE_ = 0.07216878364870323f;  // 1/sqrt(192)

__device__ __forceinline__ bf16 to_bf16(float f) {
    unsigned u = __builtin_bit_cast(unsigned, f);
    unsigned r = u + 0x7FFFu + ((u >> 16) & 1u);   // RNE
    unsigned short h = (unsigned short)(r >> 16);
    return __builtin_bit_cast(bf16, h);
}

__device__ __forceinline__ unsigned short bf16bits(float f) {
    unsigned u = __builtin_bit_cast(unsigned, f);
    unsigned r = u + 0x7FFFu + ((u >> 16) & 1u);
    return (unsigned short)(r >> 16);
}

__device__ __forceinline__ unsigned cvt_pk_bf16(float lo, float hi) {
    unsigned r;
    asm("v_cvt_pk_bf16_f32 %0, %1, %2" : "=v"(r) : "v"(lo), "v"(hi));
    return r;
}

// ---------------------------------------------------------------- batched cast f32->bf16 (7 segments, zero-pads [n, pad))
__global__ void cast_all_kernel(const float* __restrict__ s0, const float* __restrict__ s1,
                                const float* __restrict__ s2, const float* __restrict__ s3,
                                const float* __restrict__ s4, const float* __restrict__ s5,
                                const float* __restrict__ s6,
                                bf16* __restrict__ d0, bf16* __restrict__ d1, bf16* __restrict__ d2,
                                bf16* __restrict__ d3, bf16* __restrict__ d4, bf16* __restrict__ d5,
                                bf16* __restrict__ d6) {
    constexpr long ns[7]  = {8388608L, 3145728L, 1179648L, 1572864L, 12582912L, 1048576L, 4194304L};
    constexpr long pds[7] = {8388608L, 3145728L, 1310720L, 1572864L, 12582912L, 1048576L, 4194304L};
    const int seg = blockIdx.y;
    const float* in = (seg == 0) ? s0 : (seg == 1) ? s1 : (seg == 2) ? s2 : (seg == 3) ? s3
                    : (seg == 4) ? s4 : (seg == 5) ? s5 : s6;
    bf16* out = (seg == 0) ? d0 : (seg == 1) ? d1 : (seg == 2) ? d2 : (seg == 3) ? d3
              : (seg == 4) ? d4 : (seg == 5) ? d5 : d6;
    const long n = ns[seg], pad = pds[seg];
    long i = ((long)blockIdx.x * 256 + threadIdx.x) * 4;
    const long stride = (long)gridDim.x * 256 * 4;
    for (; i < pad; i += stride) {
        if (i < n) {
            float4 v = *(const float4*)(in + i);
            out[i + 0] = to_bf16(v.x); out[i + 1] = to_bf16(v.y);
            out[i + 2] = to_bf16(v.z); out[i + 3] = to_bf16(v.w);
        } else {
            out[i + 0] = to_bf16(0.f); out[i + 1] = to_bf16(0.f);
            out[i + 2] = to_bf16(0.f); out[i + 3] = to_bf16(0.f);
        }
    }
}

// ---------------------------------------------------------------- rope cos/sin table [S][32]
__global__ void rope_table_kernel(float* __restrict__ cosT, float* __restrict__ sinT) {
    int idx = blockIdx.x * 256 + threadIdx.x;
    if (idx >= S_ * 32) return;
    int s = idx >> 5, j = idx & 31;
    float invf = expf(-(float)(2 * j) * (1.0f / 64.0f) * 9.210340371976184f); // theta^(-2j/64)
    float a = (float)s * invf;
    cosT[idx] = cosf(a);
    sinT[idx] = sinf(a);
}

// ---------------------------------------------------------------- fused post: rmsnorm(q_a) + rmsnorm(ckv) + rope(k) per row
__global__ void fused_post_kernel(const float* __restrict__ scr, const float* __restrict__ qw,
                                  const float* __restrict__ kw, const float* __restrict__ cosT,
                                  const float* __restrict__ sinT, bf16* __restrict__ qab,
                                  bf16* __restrict__ ckvb, bf16* __restrict__ krb) {
    const int row = blockIdx.x;
    const int tid = threadIdx.x;
    const float* x = scr + (long)row * QKV_N;
    float ssq = 0.f, ssk = 0.f;
    for (int i = tid; i < 1536; i += 256) { float v = x[i]; ssq += v * v; }
    for (int i = tid; i < 512; i += 256) { float v = x[1536 + i]; ssk += v * v; }
#pragma unroll
    for (int d = 1; d < 64; d <<= 1) { ssq += __shfl_xor(ssq, d); ssk += __shfl_xor(ssk, d); }
    __shared__ float rq[4], rk[4];
    if ((tid & 63) == 0) { rq[tid >> 6] = ssq; rk[tid >> 6] = ssk; }
    __syncthreads();
    float rsq = rsqrtf((rq[0] + rq[1] + rq[2] + rq[3]) / 1536.f + 1e-6f);
    float rsk = rsqrtf((rk[0] + rk[1] + rk[2] + rk[3]) / 512.f + 1e-6f);
    for (int i = tid; i < 1536; i += 256)
        qab[(long)row * 1536 + i] = to_bf16(x[i] * rsq * qw[i]);
    for (int i = tid; i < 512; i += 256)
        ckvb[(long)row * 512 + i] = to_bf16(x[1536 + i] * rsk * kw[i]);
    if (tid < 64) {
        int s = row & (S_ - 1);
        const float* kr = x + 2048;
        float other = (tid < 32) ? -kr[tid + 32] : kr[tid - 32];
        float c = cosT[s * 32 + (tid & 31)], sn = sinT[s * 32 + (tid & 31)];
        krb[(long)row * 64 + tid] = to_bf16(kr[tid] * c + other * sn);
    }
}

// ---------------------------------------------------------------- GEMM 128x128 (R12 pipeline, proven): C = A * B^T
// MODE 0: f32 out; MODE 1: bf16 out x SCALE_; MODE 2: bf16 transposed out for Vt (8B packed).
template <int MODE>
__global__ __launch_bounds__(256, 2)
void gemm_bt_kernel(const bf16* __restrict__ A, const bf16* __restrict__ Bm,
                    void* __restrict__ Cout, int M, int N, int K) {
    constexpr int BK = 32;
    __shared__ bf16 As[3][128 * BK];
    __shared__ bf16 Bs[3][128 * BK];
    const int tid = threadIdx.x;
    const int w = tid >> 6;
    const int lane = tid & 63;
    const int nwg = gridDim.x * gridDim.y;
    const int lin = blockIdx.y * gridDim.x + blockIdx.x;
    const int swz = (lin & 7) * (nwg >> 3) + (lin >> 3);
    const long m0 = (long)(swz % gridDim.x) * 128;
    const long n0 = (long)(swz / gridDim.x) * 128;
    const int wm = (w >> 1) * 64, wn = (w & 1) * 64;
    const int lr = lane & 15;
    const int lk = (lane >> 4) * 8;

    const int c0 = w * 2, c1 = w * 2 + 1;
    const int srow0 = c0 * 16 + (lane >> 2);
    const int srow1 = c1 * 16 + (lane >> 2);
    const int skc = (lane & 3) * 8;
    const bf16* ga0 = A + (m0 + srow0) * (long)K + skc;
    const bf16* ga1 = A + (m0 + srow1) * (long)K + skc;
    const bf16* gb0 = Bm + (n0 + srow0) * (long)K + skc;
    const bf16* gb1 = Bm + (n0 + srow1) * (long)K + skc;

#define GSTAGE(p) do { \
    GLDS16(ga0, &As[p][c0 * 512]); \
    GLDS16(gb0, &Bs[p][c0 * 512]); \
    GLDS16(ga1, &As[p][c1 * 512]); \
    GLDS16(gb1, &Bs[p][c1 * 512]); \
    ga0 += BK; ga1 += BK; gb0 += BK; gb1 += BK; \
} while (0)

    f32x4 acc[4][4] = {};
    const int nT = K / BK;

    GSTAGE(0);
    if (nT > 1) {
        GSTAGE(1);
        asm volatile("s_waitcnt vmcnt(4)" ::: "memory");
    } else {
        asm volatile("s_waitcnt vmcnt(0)" ::: "memory");
    }
    SCHED_FENCE();
    __builtin_amdgcn_s_barrier();
    SCHED_FENCE();

    for (int t = 0; t < nT; ++t) {
        const int p = t % 3;
        if (t + 2 < nT) GSTAGE((t + 2) % 3);
        bf16x8 av[4], bv[4];
#pragma unroll
        for (int i = 0; i < 4; i++) av[i] = *(const bf16x8*)&As[p][(wm + i * 16 + lr) * BK + lk];
#pragma unroll
        for (int j = 0; j < 4; j++) bv[j] = *(const bf16x8*)&Bs[p][(wn + j * 16 + lr) * BK + lk];
#pragma unroll
        for (int i = 0; i < 4; i++)
#pragma unroll
            for (int j = 0; j < 4; j++)
                acc[i][j] = MFMA_BF16(av[i], bv[j], acc[i][j]);
        if (t + 1 < nT) {
            SCHED_FENCE();
            if (t + 2 < nT) asm volatile("s_waitcnt vmcnt(4)" ::: "memory");
            else            asm volatile("s_waitcnt vmcnt(0)" ::: "memory");
            SCHED_FENCE();
            __builtin_amdgcn_s_barrier();
            SCHED_FENCE();
        }
    }
#undef GSTAGE

    const int r4 = (lane >> 4) * 4;
#pragma unroll
    for (int i = 0; i < 4; i++)
#pragma unroll
        for (int j = 0; j < 4; j++) {
            long gmb = m0 + wm + i * 16 + r4;
            long gn = n0 + wn + j * 16 + lr;
            if (MODE == 2) {
                long idx = (gmb >> 11) * (2048L * 2048) + gn * 2048 + (gmb & 2047);
                ushort4 u;
                u.x = bf16bits(acc[i][j][0]);
                u.y = bf16bits(acc[i][j][1]);
                u.z = bf16bits(acc[i][j][2]);
                u.w = bf16bits(acc[i][j][3]);
                *(ushort4*)((bf16*)Cout + idx) = u;
            } else {
#pragma unroll
                for (int r = 0; r < 4; r++) {
                    long gm = gmb + r;
                    float v = acc[i][j][r];
                    if (MODE == 0) {
                        if (gn < N) ((float*)Cout)[gm * N + gn] = v;
                    } else {  // MODE 1
                        if (gn < N) ((bf16*)Cout)[gm * N + gn] = to_bf16(v * SCALE_);
                    }
                }
            }
        }
}

// ---------------------------------------------------------------- GEMM 256x256 8-PHASE (T3+T4+T2+T5): C = A*B^T, bf16 (R16, proven)
// MODE 1: bf16 out x SCALE_ (row stride N).
// MODE 4: merged nope_q+q_rope epilogue — blocks with n0 < 8192 write npq (stride 8192,
//   x SCALE_); blocks with n0 >= 8192 apply q-RoPE (pairs acc[i][j]/acc[i][j+2], each wave's
//   64-col span = one 64-wide head) and write qrb (stride 1024, x SCALE_).
template <int MODE>
__global__ __launch_bounds__(512, 1)
void gemm8p_kernel(const bf16* __restrict__ A, const bf16* __restrict__ Bm,
                   void* __restrict__ Cout, int M, int N, int K,
                   const float* __restrict__ cosT = nullptr,
                   const float* __restrict__ sinT = nullptr,
                   bf16* __restrict__ Cout2 = nullptr) {
    __shared__ bf16 Abuf[2][256 * 64];   // 2 x 32KB
    __shared__ bf16 Bbuf[2][256 * 64];   // 2 x 32KB  (128KB total)
    const int tid = threadIdx.x;
    const int w = tid >> 6, lane = tid & 63;
    const int wr = w >> 2, wc = w & 3;
    const int lr = lane & 15, lg = lane >> 4;
    const int nwg = gridDim.x * gridDim.y;
    const int lin = blockIdx.y * gridDim.x + blockIdx.x;
    const int swz = (lin & 7) * (nwg >> 3) + (lin >> 3);
    const long m0 = (long)(swz % gridDim.x) * 256;
    const long n0 = (long)(swz / gridDim.x) * 256;

    const int rbase = tid >> 3;                         // 0..63
    const int clb = (tid & 7) * 16;                     // byte col within 128B row
    const int elem0 = (clb ^ ((rbase & 7) << 4)) >> 1;  // swizzled source elem
    const int dstoff = rbase * 128 + clb;
    const bf16* pA = A + (m0 + rbase) * (long)K + elem0;
    const bf16* pB = Bm + (n0 + rbase) * (long)K + elem0;
    const int nK = K / 64;

#define STG8(isB, buf, kt, h) do { \
    const bf16* _s = ((isB) ? pB : pA) + (long)((h) * 128) * K + (kt) * 64; \
    char* _d = (char*)((isB) ? &Bbuf[buf][0] : &Abuf[buf][0]) + (h) * 16384 + dstoff; \
    GLDS16(_s, _d); \
    GLDS16(_s + 64L * K, _d + 8192); \
} while (0)

    const int rsw = (lr & 7) << 4;
#define ARD8(buf, i, kk) (*(const bf16x8*)((const char*)&Abuf[buf][0] + (wr * 128 + (i) * 16 + lr) * 128 + ((((kk) * 64) + lg * 16) ^ rsw)))
#define BRD8(buf, j, kk) (*(const bf16x8*)((const char*)&Bbuf[buf][0] + (wc * 64 + (j) * 16 + lr) * 128 + ((((kk) * 64) + lg * 16) ^ rsw)))

    f32x4 acc[8][4] = {};
    bf16x8 bv0[4], bv1[4];   // B-frags (kk=0 / kk=1) of the current buf, live across 4 phases

    // prologue: A(0),B(0) full + B(1) full; wait A(0)/B(0) landed (B(1)'s 4 loads in flight)
    STG8(0, 0, 0, 0); STG8(0, 0, 0, 1);
    STG8(1, 0, 0, 0); STG8(1, 0, 0, 1);
    STG8(1, 1, 1, 0); STG8(1, 1, 1, 1);
    SCHED_FENCE();
    asm volatile("s_waitcnt vmcnt(4)" ::: "memory");
    SCHED_FENCE();
    __builtin_amdgcn_s_barrier();
    SCHED_FENCE();

#define PHASE8(BUF, Q, STAGE_STMT, ENDWAIT_STMT) do { \
    bf16x8 a00 = ARD8(BUF, 2 * (Q), 0), a01 = ARD8(BUF, 2 * (Q), 1); \
    bf16x8 a10 = ARD8(BUF, 2 * (Q) + 1, 0), a11 = ARD8(BUF, 2 * (Q) + 1, 1); \
    if ((Q) == 0) { \
        _Pragma("unroll") \
        for (int j = 0; j < 4; ++j) { bv0[j] = BRD8(BUF, j, 0); bv1[j] = BRD8(BUF, j, 1); } \
    } \
    STAGE_STMT; \
    SCHED_FENCE(); \
    __builtin_amdgcn_s_barrier(); \
    SCHED_FENCE(); \
    __builtin_amdgcn_s_setprio(1); \
    _Pragma("unroll") \
    for (int j = 0; j < 4; ++j) { \
        acc[2 * (Q)][j]     = MFMA_BF16(a00, bv0[j], acc[2 * (Q)][j]); \
        acc[2 * (Q)][j]     = MFMA_BF16(a01, bv1[j], acc[2 * (Q)][j]); \
        acc[2 * (Q) + 1][j] = MFMA_BF16(a10, bv0[j], acc[2 * (Q) + 1][j]); \
        acc[2 * (Q) + 1][j] = MFMA_BF16(a11, bv1[j], acc[2 * (Q) + 1][j]); \
    } \
    __builtin_amdgcn_s_setprio(0); \
    SCHED_FENCE(); \
    ENDWAIT_STMT; \
    SCHED_FENCE(); \
    __builtin_amdgcn_s_barrier(); \
    SCHED_FENCE(); \
} while (0)

    const int nIter = nK / 2;
    for (int it = 0; it < nIter; ++it) {
        const int kt0 = 2 * it, kt1 = kt0 + 1;
        PHASE8(0, 0, STG8(0, 1, kt1, 0), (void)0);
        PHASE8(0, 1, STG8(0, 1, kt1, 1), (void)0);
        PHASE8(0, 2, if (kt0 + 2 < nK) STG8(1, 0, kt0 + 2, 0), (void)0);
        PHASE8(0, 3, if (kt0 + 2 < nK) STG8(1, 0, kt0 + 2, 1),
               asm volatile("s_waitcnt vmcnt(4)" ::: "memory"));
        PHASE8(1, 0, if (kt0 + 2 < nK) STG8(0, 0, kt0 + 2, 0), (void)0);
        PHASE8(1, 1, if (kt0 + 2 < nK) STG8(0, 0, kt0 + 2, 1), (void)0);
        PHASE8(1, 2, if (kt1 + 2 < nK) STG8(1, 1, kt1 + 2, 0), (void)0);
        PHASE8(1, 3, if (kt1 + 2 < nK) STG8(1, 1, kt1 + 2, 1),
               asm volatile("s_waitcnt vmcnt(4)" ::: "memory"));
    }
#undef PHASE8
#undef STG8
#undef ARD8
#undef BRD8

    const int r4 = lg * 4;
    if (MODE == 4 && n0 >= 8192) {
        // q-RoPE epilogue: head-internal col e = j*16+lr (j<2), partner e+32 = acc[i][j+2].
#pragma unroll
        for (int i = 0; i < 8; i++)
#pragma unroll
            for (int r = 0; r < 4; r++) {
                long gm = m0 + wr * 128 + i * 16 + r4 + r;
                int s = (int)(gm & (S_ - 1));
#pragma unroll
                for (int j = 0; j < 2; j++) {
                    float c = cosT[s * 32 + j * 16 + lr];
                    float sn = sinT[s * 32 + j * 16 + lr];
                    float lo = acc[i][j][r], hiv = acc[i][j + 2][r];
                    long col = (n0 - 8192) + wc * 64 + j * 16 + lr;
                    Cout2[gm * 1024 + col] = to_bf16((lo * c - hiv * sn) * SCALE_);
                    Cout2[gm * 1024 + col + 32] = to_bf16((hiv * c + lo * sn) * SCALE_);
                }
            }
        return;
    }
    const long ostride = (MODE == 4) ? 8192 : N;
#pragma unroll
    for (int i = 0; i < 8; i++)
#pragma unroll
        for (int j = 0; j < 4; j++) {
            long gmb = m0 + wr * 128 + i * 16 + r4;
            long gn = n0 + wc * 64 + j * 16 + lr;
#pragma unroll
            for (int r = 0; r < 4; r++) {
                long gm = gmb + r;
                float v = acc[i][j][r];
                ((bf16*)Cout)[gm * ostride + gn] = to_bf16(v * SCALE_);
            }
        }
}

// ---------------------------------------------------------------- flash attention v3c (FROZEN; verified R5/R7/R9/R11/R13/R15/R16 at 243-245us)
// launch_bounds(256,2), 57344B LDS, VGPR 128. R14: (256,3) capped VGPR at 84 < qf's 144
// live -> spill -> FETCH 120MB->1.06GB. R6/R10: stage->drain rhythm is load-bearing for
// inter-block L2 alignment. Do not perturb.
__global__ __launch_bounds__(256, 2)
void flash_kernel(const bf16* __restrict__ nopeq, const bf16* __restrict__ ropeq,
                  const bf16* __restrict__ ckv, const bf16* __restrict__ krope,
                  const bf16* __restrict__ vt, bf16* __restrict__ outa) {
    __shared__ bf16 Ks2[32 * 512];   // 32 KiB
    __shared__ bf16 Krs[32 * 64];    // 4 KiB
    __shared__ char VtsB[10240];     // 128 rows x 80B (64B data + 16B pad)
    __shared__ char PldsB[4][32 * 80]; // per-wave P buffer, 10 KiB total
    const int tid = threadIdx.x;
    const int w = tid >> 6, lane = tid & 63;
    const int l31 = lane & 31;
    const int hi = lane >> 5;
    const int kel = hi * 8;          // frag k-offset (elements)
    const int klo = hi * 16;         // frag k-offset (bytes)
    const int h = blockIdx.y, b = blockIdx.z;
    const int xq = (b == 0) ? (int)blockIdx.x : (15 - (int)blockIdx.x);  // CU work pairing
    const int q0 = xq * 128;
    const long bS = (long)b * S_;
    const int qg = q0 + (l31 << 2) + w;   // interleaved q-row of this lane
    const int kvoff = hi * 4;

    // Q fragments in registers (already scaled by SCALE_): 36 x bf16x8
    bf16x8 qf[36];
    {
        const bf16* np = nopeq + (bS + qg) * (long)(H_ * KVL_) + h * KVL_;
        const bf16* rp = ropeq + (bS + qg) * (long)(H_ * ROPE_) + h * ROPE_;
#pragma unroll
        for (int t = 0; t < 32; ++t) qf[t] = *(const bf16x8*)(np + t * 16 + kel);
#pragma unroll
        for (int t = 0; t < 4; ++t) qf[32 + t] = *(const bf16x8*)(rp + t * 16 + kel);
    }

    // staging offsets (bytes): 8 ckv chunks + 1 krope + 2-3 V chunks per wave
    unsigned soff[12];
#pragma unroll
    for (int k = 0; k < 8; ++k) {
        int c = w + 4 * k;  // one ckv row per chunk
        soff[k] = (unsigned)((bS + c) * 1024 + ((lane * 16) ^ ((c & 7) << 4)));
    }
    {
        int rr = w * 8 + (lane >> 3);
        soff[8] = (unsigned)((bS + rr) * 128 + (((lane & 7) * 16) ^ ((rr & 7) << 4)));
    }
#pragma unroll
    for (int k = 9; k < 12; ++k) {
        int cc = (k == 11) ? (8 + w) : (w + 4 * (k - 9));
        int byt = cc * 1024 + lane * 16;
        int v = byt / 80, col = byt - v * 80;
        soff[k] = (col < 64) ? (unsigned)((((long)(b * H_ + h) * VD_ + v) * S_ + (col >> 1)) * 2) : 0u;
    }

    f32x16 accv[4] = {};
    float m_run = -3e38f, l_run = 0.f;
    const int nkv = q0 / 32 + 4;
    const int kswz = (l31 & 7) << 4;

    for (int it = 0; it < nkv; ++it) {
        const int kv0 = it * 32;
        __syncthreads();   // previous tile fully consumed
#pragma unroll
        for (int k = 0; k < 8; ++k) {
            GLDS16((const char*)ckv + soff[k], (char*)Ks2 + (w + 4 * k) * 1024);
            soff[k] += 32768;
        }
        GLDS16((const char*)krope + soff[8], (char*)Krs + w * 1024);
        soff[8] += 4096;
        GLDS16((const char*)vt + soff[9], VtsB + w * 1024); soff[9] += 64;
        GLDS16((const char*)vt + soff[10], VtsB + (w + 4) * 1024); soff[10] += 64;
        if (w < 2) { GLDS16((const char*)vt + soff[11], VtsB + (8 + w) * 1024); soff[11] += 64; }
        __syncthreads();   // tile visible

        // S^T = K * Q  (32 kv x 32 q per wave; lane: col=q, rows=16 kv values)
        f32x16 sc = {};
        __builtin_amdgcn_s_setprio(1);
#pragma unroll
        for (int t = 0; t < 32; ++t) {
            bf16x8 kf = *(const bf16x8*)((const char*)Ks2 + l31 * 1024 + ((t * 32 + klo) ^ kswz));
            sc = MFMA32(kf, qf[t], sc);
        }
#pragma unroll
        for (int t = 0; t < 4; ++t) {
            bf16x8 kf = *(const bf16x8*)((const char*)Krs + l31 * 128 + ((t * 32 + klo) ^ kswz));
            sc = MFMA32(kf, qf[32 + t], sc);
        }
        __builtin_amdgcn_s_setprio(0);

        float s[16];
        if (kv0 + 31 > q0 + w) {   // wave-uniform: diagonal tile -> mask
#pragma unroll
            for (int r = 0; r < 16; ++r) {
                int kvg = kv0 + kvoff + ((r & 3) + 8 * (r >> 2));
                s[r] = (kvg > qg) ? -3e38f : sc[r];
            }
        } else {
#pragma unroll
            for (int r = 0; r < 16; ++r) s[r] = sc[r];
        }

        // row max: in-lane tree + cross-half shfl
        float m8[8];
#pragma unroll
        for (int r = 0; r < 8; ++r) m8[r] = fmaxf(s[r], s[r + 8]);
        float m4a = fmaxf(m8[0], m8[1]), m4b = fmaxf(m8[2], m8[3]);
        float m4c = fmaxf(m8[4], m8[5]), m4d = fmaxf(m8[6], m8[7]);
        float mx = fmaxf(fmaxf(m4a, m4b), fmaxf(m4c, m4d));
        mx = fmaxf(mx, __shfl_xor(mx, 32));

        float mnew = fmaxf(m_run, mx);
        float corr = __expf(m_run - mnew);
#pragma unroll
        for (int r = 0; r < 16; ++r) s[r] = __expf(s[r] - mnew);
        float r8[8];
#pragma unroll
        for (int r = 0; r < 8; ++r) r8[r] = s[r] + s[r + 8];
        float r4a = r8[0] + r8[1], r4b = r8[2] + r8[3], r4c = r8[4] + r8[5], r4d = r8[6] + r8[7];
        float rs = (r4a + r4b) + (r4c + r4d);
        rs += __shfl_xor(rs, 32);

        // rescale O (skip when no lane's max grew: corr==1 exactly)
        if (__any(mnew > m_run)) {
#pragma unroll
            for (int vg = 0; vg < 4; ++vg)
#pragma unroll
                for (int r = 0; r < 16; ++r) accv[vg][r] *= corr;
        }
        l_run = l_run * corr + rs;
        m_run = mnew;

        // P -> per-wave LDS roundtrip: lane (l31,hi) holds P[kv=(r&3)+8*(r>>2)+4hi][q=l31].
        {
            char* prow = PldsB[w] + l31 * 80;
#pragma unroll
            for (int g = 0; g < 4; ++g) {
                uint2 pk;
                pk.x = cvt_pk_bf16(s[4 * g + 0], s[4 * g + 1]);
                pk.y = cvt_pk_bf16(s[4 * g + 2], s[4 * g + 3]);
                *(uint2*)(prow + g * 16 + 8 * hi) = pk;
            }
        }
        bf16x8 pfrag[2];
#pragma unroll
        for (int c = 0; c < 2; ++c)
            pfrag[c] = *(const bf16x8*)(PldsB[w] + l31 * 80 + c * 32 + klo);

        // O^T += Vt * P
        __builtin_amdgcn_s_setprio(1);
#pragma unroll
        for (int c = 0; c < 2; ++c) {
#pragma unroll
            for (int vg = 0; vg < 4; ++vg) {
                bf16x8 vf = *(const bf16x8*)(VtsB + (vg * 32 + l31) * 80 + c * 32 + klo);
                accv[vg] = MFMA32(vf, pfrag[c], accv[vg]);
            }
        }
        __builtin_amdgcn_s_setprio(0);
    }

    // epilogue: normalize, write (b, q, h*128+v) bf16; 8B packed stores
    float invl = 1.f / l_run;
    bf16* orow = outa + (bS + qg) * (long)(H_ * VD_) + h * VD_;
#pragma unroll
    for (int vg = 0; vg < 4; ++vg)
#pragma unroll
        for (int rq = 0; rq < 4; ++rq) {
            int vb = vg * 32 + rq * 8 + kvoff;
            ushort4 u;
            u.x = __builtin_bit_cast(unsigned short, to_bf16(accv[vg][rq * 4 + 0] * invl));
            u.y = __builtin_bit_cast(unsigned short, to_bf16(accv[vg][rq * 4 + 1] * invl));
            u.z = __builtin_bit_cast(unsigned short, to_bf16(accv[vg][rq * 4 + 2] * invl));
            u.w = __builtin_bit_cast(unsigned short, to_bf16(accv[vg][rq * 4 + 3] * invl));
            *(ushort4*)(orow + vb) = u;
        }
}

// ================================================================ host
extern "C" void kernel_launch(void* const* d_in, const int* in_sizes, int n_in,
                              void* d_out, int out_size, void* d_ws, size_t ws_size,
                              hipStream_t stream) {
    const float* hidden     = (const float*)d_in[0];
    // d_in[1] = attention_mask (causal, hard-coded)
    const float* q_a_w      = (const float*)d_in[2];
    const float* q_a_ln_w   = (const float*)d_in[3];
    const float* q_b_rope_w = (const float*)d_in[4];
    const float* qk_nope_w  = (const float*)d_in[5];
    const float* kv_a_w     = (const float*)d_in[6];
    const float* kv_a_ln_w  = (const float*)d_in[7];
    const float* v_b_w      = (const float*)d_in[8];
    const float* o_w        = (const float*)d_in[9];
    // d_in[10] = position_ids (arange, hard-coded)

    char* ws = (char*)d_ws;
    size_t off = 0;
    auto alloc = [&](size_t bytes) -> void* {
        void* p = ws + off;
        off += (bytes + 255) & ~(size_t)255;
        return p;
    };
    bf16* hb     = (bf16*)alloc(4096L * 2048 * 2);   // hidden bf16
    bf16* wqakv  = (bf16*)alloc((long)QKV_N * 2048 * 2); // merged q_a_w(1536) + kv_a_w(576) + pad(64)
    bf16* wnpr   = (bf16*)alloc(9216L * 1536 * 2);   // merged qk_nope_w(8192) + q_b_rope_w(1024)
    bf16* wvb    = (bf16*)alloc(2048L * 512 * 2);
    bf16* wo     = (bf16*)alloc(2048L * 2048 * 2);
    float* f32scr = (float*)alloc(4096L * QKV_N * 4); // merged pre-norm scratch
    bf16* qab    = (bf16*)alloc(4096L * 1536 * 2);
    bf16* qrb    = (bf16*)alloc(4096L * 1024 * 2);
    bf16* npq    = (bf16*)alloc(4096L * 8192 * 2);
    bf16* ckvb   = (bf16*)alloc(4096L * 512 * 2);
    bf16* krb    = (bf16*)alloc(4096L * 64 * 2);
    bf16* vtb    = (bf16*)alloc(2L * 2048 * 2048 * 2); // Vt [b][h*128+v][s]
    bf16* aout   = (bf16*)alloc(4096L * 2048 * 2);
    float* cosT  = (float*)alloc(2048L * 32 * 4);
    float* sinT  = (float*)alloc(2048L * 32 * 4);
    (void)ws_size; (void)in_sizes; (void)n_in; (void)out_size;

    // all f32->bf16 casts in one launch + rope table
    cast_all_kernel<<<dim3(512, 7), 256, 0, stream>>>(
        hidden, q_a_w, kv_a_w, q_b_rope_w, qk_nope_w, v_b_w, o_w,
        hb, wqakv, wqakv + 1536L * 2048, wnpr + 8192L * 1536, wnpr, wvb, wo);
    rope_table_kernel<<<256, 256, 0, stream>>>(cosT, sinT);

    // merged pre-norm GEMM: [q_a_pre | ckv_full] = hidden @ [q_a_w | kv_a_w]^T  (4096 x 2176 x 2048)
    gemm_bt_kernel<0><<<dim3(32, 17), 256, 0, stream>>>(hb, wqakv, f32scr, 4096, QKV_N, 2048);
    // fused: q_a = rmsnorm(cols 0..1535); ckv = rmsnorm(cols 1536..2047); k_rope = rope(cols 2048..2111)
    fused_post_kernel<<<4096, 256, 0, stream>>>(f32scr, q_a_ln_w, kv_a_ln_w, cosT, sinT, qab, ckvb, krb);
    // merged nope_q + q_rope: [npq | rope(qrb)] = q_a @ [qk_nope_w; q_b_rope_w]^T (8-PHASE, MODE 4)
    gemm8p_kernel<4><<<dim3(16, 36), 512, 0, stream>>>(qab, wnpr, npq, 4096, 9216, 1536, cosT, sinT, qrb);
    // V_h = ckv @ v_b_w^T, stored transposed: Vt[b][n][s]
    gemm_bt_kernel<2><<<dim3(32, 16), 256, 0, stream>>>(ckvb, wvb, vtb, 4096, 2048, 512);
    // flash attention (causal), absorbed V -> aout (b, s, h*128+v)
    flash_kernel<<<dim3(16, 16, 2), 256, 0, stream>>>(npq, qrb, ckvb, krb, vtb, aout);
    // out = aout @ o_w^T (f32)
    gemm_bt_kernel<0><<<dim3(32, 16), 256, 0, stream>>>(aout, wo, (float*)d_out, 4096, 2048, 2048);
}

// Round 18
// 553.111 us; speedup vs baseline: 1.0082x; 1.0082x over previous
//
#include <hip/hip_runtime.h>
#include <hip/hip_bf16.h>

typedef __bf16 bf16;
typedef __bf16 bf16x8 __attribute__((ext_vector_type(8)));
typedef float f32x4 __attribute__((ext_vector_type(4)));
typedef float f32x16 __attribute__((ext_vector_type(16)));

#define AS3(p) ((__attribute__((address_space(3))) void*)(p))
#define AS1(p) ((const __attribute__((address_space(1))) void*)(p))
#define GLDS16(g,l) __builtin_amdgcn_global_load_lds(AS1(g), AS3(l), 16, 0, 0)
#define MFMA_BF16(a,b,c) __builtin_amdgcn_mfma_f32_16x16x32_bf16((a),(b),(c),0,0,0)
#define MFMA32(a,b,c) __builtin_amdgcn_mfma_f32_32x32x16_bf16((a),(b),(c),0,0,0)
#define SCHED_FENCE() do { __builtin_amdgcn_sched_barrier(0); asm volatile("" ::: "memory"); } while (0)

constexpr int S_ = 2048;
constexpr int H_ = 16;
constexpr int KVL_ = 512;
constexpr int ROPE_ = 64;
constexpr int VD_ = 128;
constexpr int DQK_ = 576;           // KVL + ROPE
constexpr int QKV_N = 2176;         // merged q_a(1536) + ckv(512) + krope(64) + pad(64)
constexpr float SCALE_ = 0.07216878364870323f;  // 1/sqrt(192)

__device__ __forceinline__ bf16 to_bf16(float f) {
    unsigned u = __builtin_bit_cast(unsigned, f);
    unsigned r = u + 0x7FFFu + ((u >> 16) & 1u);   // RNE
    unsigned short h = (unsigned short)(r >> 16);
    return __builtin_bit_cast(bf16, h);
}

__device__ __forceinline__ unsigned short bf16bits(float f) {
    unsigned u = __builtin_bit_cast(unsigned, f);
    unsigned r = u + 0x7FFFu + ((u >> 16) & 1u);
    return (unsigned short)(r >> 16);
}

__device__ __forceinline__ unsigned cvt_pk_bf16(float lo, float hi) {
    unsigned r;
    asm("v_cvt_pk_bf16_f32 %0, %1, %2" : "=v"(r) : "v"(lo), "v"(hi));
    return r;
}

// ---------------------------------------------------------------- batched cast f32->bf16 (7 segments) + rope table (seg 7)
__global__ void cast_all_kernel(const float* __restrict__ s0, const float* __restrict__ s1,
                                const float* __restrict__ s2, const float* __restrict__ s3,
                                const float* __restrict__ s4, const float* __restrict__ s5,
                                const float* __restrict__ s6,
                                bf16* __restrict__ d0, bf16* __restrict__ d1, bf16* __restrict__ d2,
                                bf16* __restrict__ d3, bf16* __restrict__ d4, bf16* __restrict__ d5,
                                bf16* __restrict__ d6,
                                float* __restrict__ cosT, float* __restrict__ sinT) {
    const int seg = blockIdx.y;
    if (seg == 7) {   // rope cos/sin table [S][32]
        int idx = blockIdx.x * 256 + threadIdx.x;
        if (idx < S_ * 32) {
            int s = idx >> 5, j = idx & 31;
            float invf = expf(-(float)(2 * j) * (1.0f / 64.0f) * 9.210340371976184f);
            float a = (float)s * invf;
            cosT[idx] = cosf(a);
            sinT[idx] = sinf(a);
        }
        return;
    }
    constexpr long ns[7]  = {8388608L, 3145728L, 1179648L, 1572864L, 12582912L, 1048576L, 4194304L};
    constexpr long pds[7] = {8388608L, 3145728L, 1310720L, 1572864L, 12582912L, 1048576L, 4194304L};
    const float* in = (seg == 0) ? s0 : (seg == 1) ? s1 : (seg == 2) ? s2 : (seg == 3) ? s3
                    : (seg == 4) ? s4 : (seg == 5) ? s5 : s6;
    bf16* out = (seg == 0) ? d0 : (seg == 1) ? d1 : (seg == 2) ? d2 : (seg == 3) ? d3
              : (seg == 4) ? d4 : (seg == 5) ? d5 : d6;
    const long n = ns[seg], pad = pds[seg];
    long i = ((long)blockIdx.x * 256 + threadIdx.x) * 4;
    const long stride = (long)gridDim.x * 256 * 4;
    for (; i < pad; i += stride) {
        if (i < n) {
            float4 v = *(const float4*)(in + i);
            out[i + 0] = to_bf16(v.x); out[i + 1] = to_bf16(v.y);
            out[i + 2] = to_bf16(v.z); out[i + 3] = to_bf16(v.w);
        } else {
            out[i + 0] = to_bf16(0.f); out[i + 1] = to_bf16(0.f);
            out[i + 2] = to_bf16(0.f); out[i + 3] = to_bf16(0.f);
        }
    }
}

// ---------------------------------------------------------------- fused post: rmsnorm(q_a) + rmsnorm(ckv) + rope(k) per row
__global__ void fused_post_kernel(const float* __restrict__ scr, const float* __restrict__ qw,
                                  const float* __restrict__ kw, const float* __restrict__ cosT,
                                  const float* __restrict__ sinT, bf16* __restrict__ qab,
                                  bf16* __restrict__ ckvb, bf16* __restrict__ krb) {
    const int row = blockIdx.x;
    const int tid = threadIdx.x;
    const float* x = scr + (long)row * QKV_N;
    float ssq = 0.f, ssk = 0.f;
    for (int i = tid; i < 1536; i += 256) { float v = x[i]; ssq += v * v; }
    for (int i = tid; i < 512; i += 256) { float v = x[1536 + i]; ssk += v * v; }
#pragma unroll
    for (int d = 1; d < 64; d <<= 1) { ssq += __shfl_xor(ssq, d); ssk += __shfl_xor(ssk, d); }
    __shared__ float rq[4], rk[4];
    if ((tid & 63) == 0) { rq[tid >> 6] = ssq; rk[tid >> 6] = ssk; }
    __syncthreads();
    float rsq = rsqrtf((rq[0] + rq[1] + rq[2] + rq[3]) / 1536.f + 1e-6f);
    float rsk = rsqrtf((rk[0] + rk[1] + rk[2] + rk[3]) / 512.f + 1e-6f);
    for (int i = tid; i < 1536; i += 256)
        qab[(long)row * 1536 + i] = to_bf16(x[i] * rsq * qw[i]);
    for (int i = tid; i < 512; i += 256)
        ckvb[(long)row * 512 + i] = to_bf16(x[1536 + i] * rsk * kw[i]);
    if (tid < 64) {
        int s = row & (S_ - 1);
        const float* kr = x + 2048;
        float other = (tid < 32) ? -kr[tid + 32] : kr[tid - 32];
        float c = cosT[s * 32 + (tid & 31)], sn = sinT[s * 32 + (tid & 31)];
        krb[(long)row * 64 + tid] = to_bf16(kr[tid] * c + other * sn);
    }
}

// ---------------------------------------------------------------- GEMM 128x128 (R12 pipeline, proven): C = A * B^T
// MODE 0: f32 out; MODE 1: bf16 out x SCALE_; MODE 2: bf16 transposed out for Vt (8B packed);
// MODE 3: q-RoPE fused epilogue -> bf16 out x SCALE_ (N must be 1024).
template <int MODE>
__global__ __launch_bounds__(256, 2)
void gemm_bt_kernel(const bf16* __restrict__ A, const bf16* __restrict__ Bm,
                    void* __restrict__ Cout, int M, int N, int K,
                    const float* __restrict__ cosT = nullptr,
                    const float* __restrict__ sinT = nullptr) {
    constexpr int BK = 32;
    __shared__ bf16 As[3][128 * BK];
    __shared__ bf16 Bs[3][128 * BK];
    const int tid = threadIdx.x;
    const int w = tid >> 6;
    const int lane = tid & 63;
    const int nwg = gridDim.x * gridDim.y;
    const int lin = blockIdx.y * gridDim.x + blockIdx.x;
    const int swz = (lin & 7) * (nwg >> 3) + (lin >> 3);
    const long m0 = (long)(swz % gridDim.x) * 128;
    const long n0 = (long)(swz / gridDim.x) * 128;
    const int wm = (w >> 1) * 64, wn = (w & 1) * 64;
    const int lr = lane & 15;
    const int lk = (lane >> 4) * 8;

    const int c0 = w * 2, c1 = w * 2 + 1;
    const int srow0 = c0 * 16 + (lane >> 2);
    const int srow1 = c1 * 16 + (lane >> 2);
    const int skc = (lane & 3) * 8;
    const bf16* ga0 = A + (m0 + srow0) * (long)K + skc;
    const bf16* ga1 = A + (m0 + srow1) * (long)K + skc;
    const bf16* gb0 = Bm + (n0 + srow0) * (long)K + skc;
    const bf16* gb1 = Bm + (n0 + srow1) * (long)K + skc;

#define GSTAGE(p) do { \
    GLDS16(ga0, &As[p][c0 * 512]); \
    GLDS16(gb0, &Bs[p][c0 * 512]); \
    GLDS16(ga1, &As[p][c1 * 512]); \
    GLDS16(gb1, &Bs[p][c1 * 512]); \
    ga0 += BK; ga1 += BK; gb0 += BK; gb1 += BK; \
} while (0)

    f32x4 acc[4][4] = {};
    const int nT = K / BK;

    GSTAGE(0);
    if (nT > 1) {
        GSTAGE(1);
        asm volatile("s_waitcnt vmcnt(4)" ::: "memory");
    } else {
        asm volatile("s_waitcnt vmcnt(0)" ::: "memory");
    }
    SCHED_FENCE();
    __builtin_amdgcn_s_barrier();
    SCHED_FENCE();

    for (int t = 0; t < nT; ++t) {
        const int p = t % 3;
        if (t + 2 < nT) GSTAGE((t + 2) % 3);
        bf16x8 av[4], bv[4];
#pragma unroll
        for (int i = 0; i < 4; i++) av[i] = *(const bf16x8*)&As[p][(wm + i * 16 + lr) * BK + lk];
#pragma unroll
        for (int j = 0; j < 4; j++) bv[j] = *(const bf16x8*)&Bs[p][(wn + j * 16 + lr) * BK + lk];
#pragma unroll
        for (int i = 0; i < 4; i++)
#pragma unroll
            for (int j = 0; j < 4; j++)
                acc[i][j] = MFMA_BF16(av[i], bv[j], acc[i][j]);
        if (t + 1 < nT) {
            SCHED_FENCE();
            if (t + 2 < nT) asm volatile("s_waitcnt vmcnt(4)" ::: "memory");
            else            asm volatile("s_waitcnt vmcnt(0)" ::: "memory");
            SCHED_FENCE();
            __builtin_amdgcn_s_barrier();
            SCHED_FENCE();
        }
    }
#undef GSTAGE

    const int r4 = (lane >> 4) * 4;
    if (MODE == 3) {
#pragma unroll
        for (int i = 0; i < 4; i++)
#pragma unroll
            for (int r = 0; r < 4; r++) {
                long gm = m0 + wm + i * 16 + r4 + r;
                int s = (int)(gm & (S_ - 1));
#pragma unroll
                for (int j = 0; j < 2; j++) {
                    float c = cosT[s * 32 + j * 16 + lr];
                    float sn = sinT[s * 32 + j * 16 + lr];
                    float lo = acc[i][j][r], hiv = acc[i][j + 2][r];
                    long gn = n0 + wn + j * 16 + lr;
                    ((bf16*)Cout)[gm * 1024 + gn] = to_bf16((lo * c - hiv * sn) * SCALE_);
                    ((bf16*)Cout)[gm * 1024 + gn + 32] = to_bf16((hiv * c + lo * sn) * SCALE_);
                }
            }
        return;
    }
#pragma unroll
    for (int i = 0; i < 4; i++)
#pragma unroll
        for (int j = 0; j < 4; j++) {
            long gmb = m0 + wm + i * 16 + r4;
            long gn = n0 + wn + j * 16 + lr;
            if (MODE == 2) {
                long idx = (gmb >> 11) * (2048L * 2048) + gn * 2048 + (gmb & 2047);
                ushort4 u;
                u.x = bf16bits(acc[i][j][0]);
                u.y = bf16bits(acc[i][j][1]);
                u.z = bf16bits(acc[i][j][2]);
                u.w = bf16bits(acc[i][j][3]);
                *(ushort4*)((bf16*)Cout + idx) = u;
            } else {
#pragma unroll
                for (int r = 0; r < 4; r++) {
                    long gm = gmb + r;
                    float v = acc[i][j][r];
                    if (MODE == 0) {
                        if (gn < N) ((float*)Cout)[gm * N + gn] = v;
                    } else {  // MODE 1
                        if (gn < N) ((bf16*)Cout)[gm * N + gn] = to_bf16(v * SCALE_);
                    }
                }
            }
        }
}

// ---------------------------------------------------------------- GEMM 256x256 8-PHASE (T3+T4+T2+T5), proven R16
// MODE 1: bf16 out x SCALE_ (row stride N).
template <int MODE>
__global__ __launch_bounds__(512, 1)
void gemm8p_kernel(const bf16* __restrict__ A, const bf16* __restrict__ Bm,
                   void* __restrict__ Cout, int M, int N, int K) {
    __shared__ bf16 Abuf[2][256 * 64];   // 2 x 32KB
    __shared__ bf16 Bbuf[2][256 * 64];   // 2 x 32KB  (128KB total)
    const int tid = threadIdx.x;
    const int w = tid >> 6, lane = tid & 63;
    const int wr = w >> 2, wc = w & 3;
    const int lr = lane & 15, lg = lane >> 4;
    const int nwg = gridDim.x * gridDim.y;
    const int lin = blockIdx.y * gridDim.x + blockIdx.x;
    const int swz = (lin & 7) * (nwg >> 3) + (lin >> 3);
    const long m0 = (long)(swz % gridDim.x) * 256;
    const long n0 = (long)(swz / gridDim.x) * 256;

    const int rbase = tid >> 3;                         // 0..63
    const int clb = (tid & 7) * 16;                     // byte col within 128B row
    const int elem0 = (clb ^ ((rbase & 7) << 4)) >> 1;  // swizzled source elem
    const int dstoff = rbase * 128 + clb;
    const bf16* pA = A + (m0 + rbase) * (long)K + elem0;
    const bf16* pB = Bm + (n0 + rbase) * (long)K + elem0;
    const int nK = K / 64;

#define STG8(isB, buf, kt, h) do { \
    const bf16* _s = ((isB) ? pB : pA) + (long)((h) * 128) * K + (kt) * 64; \
    char* _d = (char*)((isB) ? &Bbuf[buf][0] : &Abuf[buf][0]) + (h) * 16384 + dstoff; \
    GLDS16(_s, _d); \
    GLDS16(_s + 64L * K, _d + 8192); \
} while (0)

    const int rsw = (lr & 7) << 4;
#define ARD8(buf, i, kk) (*(const bf16x8*)((const char*)&Abuf[buf][0] + (wr * 128 + (i) * 16 + lr) * 128 + ((((kk) * 64) + lg * 16) ^ rsw)))
#define BRD8(buf, j, kk) (*(const bf16x8*)((const char*)&Bbuf[buf][0] + (wc * 64 + (j) * 16 + lr) * 128 + ((((kk) * 64) + lg * 16) ^ rsw)))

    f32x4 acc[8][4] = {};
    bf16x8 bv0[4], bv1[4];   // B-frags (kk=0 / kk=1) of the current buf, live across 4 phases

    // prologue: A(0),B(0) full + B(1) full; wait A(0)/B(0) landed (B(1)'s 4 loads in flight)
    STG8(0, 0, 0, 0); STG8(0, 0, 0, 1);
    STG8(1, 0, 0, 0); STG8(1, 0, 0, 1);
    STG8(1, 1, 1, 0); STG8(1, 1, 1, 1);
    SCHED_FENCE();
    asm volatile("s_waitcnt vmcnt(4)" ::: "memory");
    SCHED_FENCE();
    __builtin_amdgcn_s_barrier();
    SCHED_FENCE();

#define PHASE8(BUF, Q, STAGE_STMT, ENDWAIT_STMT) do { \
    bf16x8 a00 = ARD8(BUF, 2 * (Q), 0), a01 = ARD8(BUF, 2 * (Q), 1); \
    bf16x8 a10 = ARD8(BUF, 2 * (Q) + 1, 0), a11 = ARD8(BUF, 2 * (Q) + 1, 1); \
    if ((Q) == 0) { \
        _Pragma("unroll") \
        for (int j = 0; j < 4; ++j) { bv0[j] = BRD8(BUF, j, 0); bv1[j] = BRD8(BUF, j, 1); } \
    } \
    STAGE_STMT; \
    SCHED_FENCE(); \
    __builtin_amdgcn_s_barrier(); \
    SCHED_FENCE(); \
    __builtin_amdgcn_s_setprio(1); \
    _Pragma("unroll") \
    for (int j = 0; j < 4; ++j) { \
        acc[2 * (Q)][j]     = MFMA_BF16(a00, bv0[j], acc[2 * (Q)][j]); \
        acc[2 * (Q)][j]     = MFMA_BF16(a01, bv1[j], acc[2 * (Q)][j]); \
        acc[2 * (Q) + 1][j] = MFMA_BF16(a10, bv0[j], acc[2 * (Q) + 1][j]); \
        acc[2 * (Q) + 1][j] = MFMA_BF16(a11, bv1[j], acc[2 * (Q) + 1][j]); \
    } \
    __builtin_amdgcn_s_setprio(0); \
    SCHED_FENCE(); \
    ENDWAIT_STMT; \
    SCHED_FENCE(); \
    __builtin_amdgcn_s_barrier(); \
    SCHED_FENCE(); \
} while (0)

    const int nIter = nK / 2;
    for (int it = 0; it < nIter; ++it) {
        const int kt0 = 2 * it, kt1 = kt0 + 1;
        PHASE8(0, 0, STG8(0, 1, kt1, 0), (void)0);
        PHASE8(0, 1, STG8(0, 1, kt1, 1), (void)0);
        PHASE8(0, 2, if (kt0 + 2 < nK) STG8(1, 0, kt0 + 2, 0), (void)0);
        PHASE8(0, 3, if (kt0 + 2 < nK) STG8(1, 0, kt0 + 2, 1),
               asm volatile("s_waitcnt vmcnt(4)" ::: "memory"));
        PHASE8(1, 0, if (kt0 + 2 < nK) STG8(0, 0, kt0 + 2, 0), (void)0);
        PHASE8(1, 1, if (kt0 + 2 < nK) STG8(0, 0, kt0 + 2, 1), (void)0);
        PHASE8(1, 2, if (kt1 + 2 < nK) STG8(1, 1, kt1 + 2, 0), (void)0);
        PHASE8(1, 3, if (kt1 + 2 < nK) STG8(1, 1, kt1 + 2, 1),
               asm volatile("s_waitcnt vmcnt(4)" ::: "memory"));
    }
#undef PHASE8
#undef STG8
#undef ARD8
#undef BRD8

    // epilogue: C write (MODE 1: bf16 x SCALE_)
    const int r4 = lg * 4;
#pragma unroll
    for (int i = 0; i < 8; i++)
#pragma unroll
        for (int j = 0; j < 4; j++) {
            long gmb = m0 + wr * 128 + i * 16 + r4;
            long gn = n0 + wc * 64 + j * 16 + lr;
#pragma unroll
            for (int r = 0; r < 4; r++) {
                long gm = gmb + r;
                float v = acc[i][j][r];
                if (MODE == 0) ((float*)Cout)[gm * N + gn] = v;
                else           ((bf16*)Cout)[gm * N + gn] = to_bf16(v * SCALE_);
            }
        }
}

// ---------------------------------------------------------------- flash attention v3c (FROZEN; verified at 243-245us across 7 rounds)
// launch_bounds(256,2), 57344B LDS, VGPR 128. R14: (256,3) capped VGPR at 84 < qf's 144
// live -> spill -> FETCH 120MB->1.06GB. R6/R10: stage->drain rhythm is load-bearing for
// inter-block L2 alignment on the 512-way-shared ckv/vt streams. Do not perturb.
__global__ __launch_bounds__(256, 2)
void flash_kernel(const bf16* __restrict__ nopeq, const bf16* __restrict__ ropeq,
                  const bf16* __restrict__ ckv, const bf16* __restrict__ krope,
                  const bf16* __restrict__ vt, bf16* __restrict__ outa) {
    __shared__ bf16 Ks2[32 * 512];   // 32 KiB
    __shared__ bf16 Krs[32 * 64];    // 4 KiB
    __shared__ char VtsB[10240];     // 128 rows x 80B (64B data + 16B pad)
    __shared__ char PldsB[4][32 * 80]; // per-wave P buffer, 10 KiB total
    const int tid = threadIdx.x;
    const int w = tid >> 6, lane = tid & 63;
    const int l31 = lane & 31;
    const int hi = lane >> 5;
    const int kel = hi * 8;          // frag k-offset (elements)
    const int klo = hi * 16;         // frag k-offset (bytes)
    const int h = blockIdx.y, b = blockIdx.z;
    const int xq = (b == 0) ? (int)blockIdx.x : (15 - (int)blockIdx.x);  // CU work pairing
    const int q0 = xq * 128;
    const long bS = (long)b * S_;
    const int qg = q0 + (l31 << 2) + w;   // interleaved q-row of this lane
    const int kvoff = hi * 4;

    // Q fragments in registers (already scaled by SCALE_): 36 x bf16x8
    bf16x8 qf[36];
    {
        const bf16* np = nopeq + (bS + qg) * (long)(H_ * KVL_) + h * KVL_;
        const bf16* rp = ropeq + (bS + qg) * (long)(H_ * ROPE_) + h * ROPE_;
#pragma unroll
        for (int t = 0; t < 32; ++t) qf[t] = *(const bf16x8*)(np + t * 16 + kel);
#pragma unroll
        for (int t = 0; t < 4; ++t) qf[32 + t] = *(const bf16x8*)(rp + t * 16 + kel);
    }

    // staging offsets (bytes): 8 ckv chunks + 1 krope + 2-3 V chunks per wave
    unsigned soff[12];
#pragma unroll
    for (int k = 0; k < 8; ++k) {
        int c = w + 4 * k;  // one ckv row per chunk
        soff[k] = (unsigned)((bS + c) * 1024 + ((lane * 16) ^ ((c & 7) << 4)));
    }
    {
        int rr = w * 8 + (lane >> 3);
        soff[8] = (unsigned)((bS + rr) * 128 + (((lane & 7) * 16) ^ ((rr & 7) << 4)));
    }
#pragma unroll
    for (int k = 9; k < 12; ++k) {
        int cc = (k == 11) ? (8 + w) : (w + 4 * (k - 9));
        int byt = cc * 1024 + lane * 16;
        int v = byt / 80, col = byt - v * 80;
        soff[k] = (col < 64) ? (unsigned)((((long)(b * H_ + h) * VD_ + v) * S_ + (col >> 1)) * 2) : 0u;
    }

    f32x16 accv[4] = {};
    float m_run = -3e38f, l_run = 0.f;
    const int nkv = q0 / 32 + 4;
    const int kswz = (l31 & 7) << 4;

    for (int it = 0; it < nkv; ++it) {
        const int kv0 = it * 32;
        __syncthreads();   // previous tile fully consumed
#pragma unroll
        for (int k = 0; k < 8; ++k) {
            GLDS16((const char*)ckv + soff[k], (char*)Ks2 + (w + 4 * k) * 1024);
            soff[k] += 32768;
        }
        GLDS16((const char*)krope + soff[8], (char*)Krs + w * 1024);
        soff[8] += 4096;
        GLDS16((const char*)vt + soff[9], VtsB + w * 1024); soff[9] += 64;
        GLDS16((const char*)vt + soff[10], VtsB + (w + 4) * 1024); soff[10] += 64;
        if (w < 2) { GLDS16((const char*)vt + soff[11], VtsB + (8 + w) * 1024); soff[11] += 64; }
        __syncthreads();   // tile visible

        // S^T = K * Q  (32 kv x 32 q per wave; lane: col=q, rows=16 kv values)
        f32x16 sc = {};
        __builtin_amdgcn_s_setprio(1);
#pragma unroll
        for (int t = 0; t < 32; ++t) {
            bf16x8 kf = *(const bf16x8*)((const char*)Ks2 + l31 * 1024 + ((t * 32 + klo) ^ kswz));
            sc = MFMA32(kf, qf[t], sc);
        }
#pragma unroll
        for (int t = 0; t < 4; ++t) {
            bf16x8 kf = *(const bf16x8*)((const char*)Krs + l31 * 128 + ((t * 32 + klo) ^ kswz));
            sc = MFMA32(kf, qf[32 + t], sc);
        }
        __builtin_amdgcn_s_setprio(0);

        float s[16];
        if (kv0 + 31 > q0 + w) {   // wave-uniform: diagonal tile -> mask
#pragma unroll
            for (int r = 0; r < 16; ++r) {
                int kvg = kv0 + kvoff + ((r & 3) + 8 * (r >> 2));
                s[r] = (kvg > qg) ? -3e38f : sc[r];
            }
        } else {
#pragma unroll
            for (int r = 0; r < 16; ++r) s[r] = sc[r];
        }

        // row max: in-lane tree + cross-half shfl
        float m8[8];
#pragma unroll
        for (int r = 0; r < 8; ++r) m8[r] = fmaxf(s[r], s[r + 8]);
        float m4a = fmaxf(m8[0], m8[1]), m4b = fmaxf(m8[2], m8[3]);
        float m4c = fmaxf(m8[4], m8[5]), m4d = fmaxf(m8[6], m8[7]);
        float mx = fmaxf(fmaxf(m4a, m4b), fmaxf(m4c, m4d));
        mx = fmaxf(mx, __shfl_xor(mx, 32));

        float mnew = fmaxf(m_run, mx);
        float corr = __expf(m_run - mnew);
#pragma unroll
        for (int r = 0; r < 16; ++r) s[r] = __expf(s[r] - mnew);
        float r8[8];
#pragma unroll
        for (int r = 0; r < 8; ++r) r8[r] = s[r] + s[r + 8];
        float r4a = r8[0] + r8[1], r4b = r8[2] + r8[3], r4c = r8[4] + r8[5], r4d = r8[6] + r8[7];
        float rs = (r4a + r4b) + (r4c + r4d);
        rs += __shfl_xor(rs, 32);

        // rescale O (skip when no lane's max grew: corr==1 exactly)
        if (__any(mnew > m_run)) {
#pragma unroll
            for (int vg = 0; vg < 4; ++vg)
#pragma unroll
                for (int r = 0; r < 16; ++r) accv[vg][r] *= corr;
        }
        l_run = l_run * corr + rs;
        m_run = mnew;

        // P -> per-wave LDS roundtrip: lane (l31,hi) holds P[kv=(r&3)+8*(r>>2)+4hi][q=l31].
        {
            char* prow = PldsB[w] + l31 * 80;
#pragma unroll
            for (int g = 0; g < 4; ++g) {
                uint2 pk;
                pk.x = cvt_pk_bf16(s[4 * g + 0], s[4 * g + 1]);
                pk.y = cvt_pk_bf16(s[4 * g + 2], s[4 * g + 3]);
                *(uint2*)(prow + g * 16 + 8 * hi) = pk;
            }
        }
        bf16x8 pfrag[2];
#pragma unroll
        for (int c = 0; c < 2; ++c)
            pfrag[c] = *(const bf16x8*)(PldsB[w] + l31 * 80 + c * 32 + klo);

        // O^T += Vt * P
        __builtin_amdgcn_s_setprio(1);
#pragma unroll
        for (int c = 0; c < 2; ++c) {
#pragma unroll
            for (int vg = 0; vg < 4; ++vg) {
                bf16x8 vf = *(const bf16x8*)(VtsB + (vg * 32 + l31) * 80 + c * 32 + klo);
                accv[vg] = MFMA32(vf, pfrag[c], accv[vg]);
            }
        }
        __builtin_amdgcn_s_setprio(0);
    }

    // epilogue: normalize, write (b, q, h*128+v) bf16; 8B packed stores
    float invl = 1.f / l_run;
    bf16* orow = outa + (bS + qg) * (long)(H_ * VD_) + h * VD_;
#pragma unroll
    for (int vg = 0; vg < 4; ++vg)
#pragma unroll
        for (int rq = 0; rq < 4; ++rq) {
            int vb = vg * 32 + rq * 8 + kvoff;
            ushort4 u;
            u.x = __builtin_bit_cast(unsigned short, to_bf16(accv[vg][rq * 4 + 0] * invl));
            u.y = __builtin_bit_cast(unsigned short, to_bf16(accv[vg][rq * 4 + 1] * invl));
            u.z = __builtin_bit_cast(unsigned short, to_bf16(accv[vg][rq * 4 + 2] * invl));
            u.w = __builtin_bit_cast(unsigned short, to_bf16(accv[vg][rq * 4 + 3] * invl));
            *(ushort4*)(orow + vb) = u;
        }
}

// ================================================================ host
extern "C" void kernel_launch(void* const* d_in, const int* in_sizes, int n_in,
                              void* d_out, int out_size, void* d_ws, size_t ws_size,
                              hipStream_t stream) {
    const float* hidden     = (const float*)d_in[0];
    // d_in[1] = attention_mask (causal, hard-coded)
    const float* q_a_w      = (const float*)d_in[2];
    const float* q_a_ln_w   = (const float*)d_in[3];
    const float* q_b_rope_w = (const float*)d_in[4];
    const float* qk_nope_w  = (const float*)d_in[5];
    const float* kv_a_w     = (const float*)d_in[6];
    const float* kv_a_ln_w  = (const float*)d_in[7];
    const float* v_b_w      = (const float*)d_in[8];
    const float* o_w        = (const float*)d_in[9];
    // d_in[10] = position_ids (arange, hard-coded)

    char* ws = (char*)d_ws;
    size_t off = 0;
    auto alloc = [&](size_t bytes) -> void* {
        void* p = ws + off;
        off += (bytes + 255) & ~(size_t)255;
        return p;
    };
    bf16* hb     = (bf16*)alloc(4096L * 2048 * 2);   // hidden bf16
    bf16* wqakv  = (bf16*)alloc((long)QKV_N * 2048 * 2); // merged q_a_w(1536) + kv_a_w(576) + pad(64)
    bf16* wqr    = (bf16*)alloc(1024L * 1536 * 2);
    bf16* wnp    = (bf16*)alloc(8192L * 1536 * 2);
    bf16* wvb    = (bf16*)alloc(2048L * 512 * 2);
    bf16* wo     = (bf16*)alloc(2048L * 2048 * 2);
    float* f32scr = (float*)alloc(4096L * QKV_N * 4); // merged pre-norm scratch
    bf16* qab    = (bf16*)alloc(4096L * 1536 * 2);
    bf16* qrb    = (bf16*)alloc(4096L * 1024 * 2);
    bf16* npq    = (bf16*)alloc(4096L * 8192 * 2);
    bf16* ckvb   = (bf16*)alloc(4096L * 512 * 2);
    bf16* krb    = (bf16*)alloc(4096L * 64 * 2);
    bf16* vtb    = (bf16*)alloc(2L * 2048 * 2048 * 2); // Vt [b][h*128+v][s]
    bf16* aout   = (bf16*)alloc(4096L * 2048 * 2);
    float* cosT  = (float*)alloc(2048L * 32 * 4);
    float* sinT  = (float*)alloc(2048L * 32 * 4);
    (void)ws_size; (void)in_sizes; (void)n_in; (void)out_size;

    // all f32->bf16 casts + rope table in ONE launch (seg 7 = table)
    cast_all_kernel<<<dim3(512, 8), 256, 0, stream>>>(
        hidden, q_a_w, kv_a_w, q_b_rope_w, qk_nope_w, v_b_w, o_w,
        hb, wqakv, wqakv + 1536L * 2048, wqr, wnp, wvb, wo, cosT, sinT);

    // merged pre-norm GEMM: [q_a_pre | ckv_full] = hidden @ [q_a_w | kv_a_w]^T  (4096 x 2176 x 2048)
    gemm_bt_kernel<0><<<dim3(32, 17), 256, 0, stream>>>(hb, wqakv, f32scr, 4096, QKV_N, 2048);
    // fused: q_a = rmsnorm(cols 0..1535); ckv = rmsnorm(cols 1536..2047); k_rope = rope(cols 2048..2111)
    fused_post_kernel<<<4096, 256, 0, stream>>>(f32scr, q_a_ln_w, kv_a_ln_w, cosT, sinT, qab, ckvb, krb);
    // q_rope = rope(q_a @ q_b_rope_w^T) x SCALE_, RoPE fused into the GEMM epilogue (MODE 3)
    gemm_bt_kernel<3><<<dim3(32, 8), 256, 0, stream>>>(qab, wqr, qrb, 4096, 1024, 1536, cosT, sinT);
    // nope_q = q_a @ qk_nope_w^T (bf16 out, scaled by SCALE_) — 8-PHASE 256x256 kernel
    gemm8p_kernel<1><<<dim3(16, 32), 512, 0, stream>>>(qab, wnp, npq, 4096, 8192, 1536);
    // V_h = ckv @ v_b_w^T, stored transposed: Vt[b][n][s]
    gemm_bt_kernel<2><<<dim3(32, 16), 256, 0, stream>>>(ckvb, wvb, vtb, 4096, 2048, 512);
    // flash attention (causal), absorbed V -> aout (b, s, h*128+v)
    flash_kernel<<<dim3(16, 16, 2), 256, 0, stream>>>(npq, qrb, ckvb, krb, vtb, aout);
    // out = aout @ o_w^T (f32)
    gemm_bt_kernel<0><<<dim3(32, 16), 256, 0, stream>>>(aout, wo, (float*)d_out, 4096, 2048, 2048);
}